// Round 6
// baseline (897.922 us; speedup 1.0000x reference)
//
#include <hip/hip_runtime.h>
#include <math.h>
#include <stdint.h>

#define B_  4
#define S_  2048
#define D_  1024
#define H_  16
#define DK_ 64
#define NR_ (B_ * S_)   // 8192 rows

typedef _Float16 half8  __attribute__((ext_vector_type(8)));
typedef _Float16 half4  __attribute__((ext_vector_type(4)));
typedef float    floatx4 __attribute__((ext_vector_type(4)));

// ---------------------------------------------------------------------------
// One-time fp32 -> split-f16 (hi/lo planes) for GEMM X inputs. Memory-bound.
// ---------------------------------------------------------------------------
__global__ __launch_bounds__(256)
void split_f32(const float* __restrict__ src, _Float16* __restrict__ hi,
               _Float16* __restrict__ lo, int n8) {
    const int i = blockIdx.x * 256 + threadIdx.x;
    if (i >= n8) return;
    const float4* s4 = (const float4*)src;
    float4 a = s4[2 * i];
    float4 b = s4[2 * i + 1];
    float f[8] = {a.x, a.y, a.z, a.w, b.x, b.y, b.z, b.w};
    union { half8 v; _Float16 h[8]; } H, L;
    #pragma unroll
    for (int j = 0; j < 8; ++j) {
        _Float16 h = (_Float16)f[j];
        H.h[j] = h;
        L.h[j] = (_Float16)(f[j] - (float)h);
    }
    *(half8*)(hi + (size_t)i * 8) = H.v;
    *(half8*)(lo + (size_t)i * 8) = L.v;
}

// Batched weight split: all 4 weights in one launch (blockIdx.y selects).
__global__ __launch_bounds__(256)
void split_w4(const float* __restrict__ w0, const float* __restrict__ w1,
              const float* __restrict__ w2, const float* __restrict__ w3,
              _Float16* __restrict__ wbase, int n8) {
    const int i = blockIdx.x * 256 + threadIdx.x;
    if (i >= n8) return;
    const float* src = (blockIdx.y == 0) ? w0 : (blockIdx.y == 1) ? w1 :
                       (blockIdx.y == 2) ? w2 : w3;
    _Float16* hi = wbase + (size_t)blockIdx.y * 2 * ((size_t)D_ * D_);
    _Float16* lo = hi + (size_t)D_ * D_;
    const float4* s4 = (const float4*)src;
    float4 a = s4[2 * i];
    float4 b = s4[2 * i + 1];
    float f[8] = {a.x, a.y, a.z, a.w, b.x, b.y, b.z, b.w};
    union { half8 v; _Float16 h[8]; } H, L;
    #pragma unroll
    for (int j = 0; j < 8; ++j) {
        _Float16 h = (_Float16)f[j];
        H.h[j] = h;
        L.h[j] = (_Float16)(f[j] - (float)h);
    }
    *(half8*)(hi + (size_t)i * 8) = H.v;
    *(half8*)(lo + (size_t)i * 8) = L.v;
}

// ---------------------------------------------------------------------------
// GEMM: out = X @ W^T via split-f16 MFMA (fp32-accurate), tile 128x128.
// A-fragments load directly global->register; only W staged in LDS.
// Round-6: GBK 32 -> 64. Theory: the 2-barrier-per-K-step structure pays a
// fixed waitcnt-drain per iteration (the documented ~36%-of-peak ceiling);
// per-byte rates are unchanged by BK, so halving the iteration count (32->16)
// halves the drain overhead. LDS 37 KB -> still 4 blocks/CU.
// apack=1: A input is packed u32 {lo16,hi16} (attention output) -> unpack
// in-register during the A prefetch (hidden under 96 MFMAs/iter).
// Epilogue modes:
//   0: fp32 [N x M] row-major                        (Wo projection -> d_out)
//   1: packed u32 {lo16,hi16} f16 split, [B,H,S,DK]  (Q,K projections)
//   2: f16 transposed head-split [B,H,DK,S]          (V projection)
// ---------------------------------------------------------------------------
#define GBN 128
#define GBM 128
#define GBK 64
#define LDH 72

__global__ __launch_bounds__(256, 3)
void gemm_xwt_mfma(const _Float16* __restrict__ Xh, const _Float16* __restrict__ Xl,
                   const _Float16* __restrict__ Wh, const _Float16* __restrict__ Wl,
                   void* __restrict__ out0, int mode, int apack) {
    __shared__ __align__(16) _Float16 Whi[GBM][LDH];
    __shared__ __align__(16) _Float16 Wlo[GBM][LDH];
    const int K = D_;

    const int tid  = threadIdx.x;
    const int wave = tid >> 6;
    const int lane = tid & 63;
    const int row16 = lane & 15;
    const int quad  = lane >> 4;
    const int n0 = blockIdx.x * GBN;
    const int m0 = blockIdx.y * GBM;

    // W staging map: 128 rows x 64 halves/plane, 2 threads/row (32 halves each)
    const int wrow = tid >> 1;
    const int wc   = (tid & 1) << 5;

    // A bases: lane (row16,quad) covers X[n0+wave*32+ni*16+row16][k0+ks*32+quad*8..+8]
    const _Float16* aHb = Xh + (size_t)(n0 + wave * 32 + row16) * K + quad * 8;
    const _Float16* aLb = Xl + (size_t)(n0 + wave * 32 + row16) * K + quad * 8;
    const uint32_t* aPb = (const uint32_t*)Xh + (size_t)(n0 + wave * 32 + row16) * K + quad * 8;

    floatx4 acc[2][8];
    const floatx4 zero4 = {0.f, 0.f, 0.f, 0.f};
    #pragma unroll
    for (int i = 0; i < 2; ++i)
        #pragma unroll
        for (int j = 0; j < 8; ++j) acc[i][j] = zero4;

    half8 pa_h[2][2], pa_l[2][2];   // [ni][ks]
    uint4 wh[4], wl[4];
    auto load_regs = [&](int k0) {
        if (apack) {
            #pragma unroll
            for (int ni = 0; ni < 2; ++ni)
                #pragma unroll
                for (int ks = 0; ks < 2; ++ks) {
                    const uint32_t* p = aPb + (size_t)ni * 16 * K + k0 + ks * 32;
                    uint32_t u[8];
                    *(uint4*)&u[0] = *(const uint4*)p;
                    *(uint4*)&u[4] = *(const uint4*)(p + 4);
                    union { half8 v; uint16_t s[8]; } hi, lo;
                    #pragma unroll
                    for (int j = 0; j < 8; ++j) {
                        hi.s[j] = (uint16_t)(u[j] & 0xffffu);
                        lo.s[j] = (uint16_t)(u[j] >> 16);
                    }
                    pa_h[ni][ks] = hi.v;
                    pa_l[ni][ks] = lo.v;
                }
        } else {
            #pragma unroll
            for (int ni = 0; ni < 2; ++ni)
                #pragma unroll
                for (int ks = 0; ks < 2; ++ks) {
                    pa_h[ni][ks] = *(const half8*)(aHb + (size_t)ni * 16 * K + k0 + ks * 32);
                    pa_l[ni][ks] = *(const half8*)(aLb + (size_t)ni * 16 * K + k0 + ks * 32);
                }
        }
        const _Float16* pwh = Wh + (size_t)(m0 + wrow) * K + k0 + wc;
        const _Float16* pwl = Wl + (size_t)(m0 + wrow) * K + k0 + wc;
        #pragma unroll
        for (int c = 0; c < 4; ++c) {
            wh[c] = *(const uint4*)(pwh + c * 8);
            wl[c] = *(const uint4*)(pwl + c * 8);
        }
    };

    load_regs(0);
    for (int k0 = 0; k0 < K; k0 += GBK) {
        // capture current A-frags before prefetch overwrites them
        half8 a_hi[2][2], a_lo[2][2];
        #pragma unroll
        for (int ni = 0; ni < 2; ++ni)
            #pragma unroll
            for (int ks = 0; ks < 2; ++ks) {
                a_hi[ni][ks] = pa_h[ni][ks];
                a_lo[ni][ks] = pa_l[ni][ks];
            }
        __syncthreads();                 // prev iteration's b-reads done
        #pragma unroll
        for (int c = 0; c < 4; ++c) {
            *(uint4*)&Whi[wrow][wc + c * 8] = wh[c];
            *(uint4*)&Wlo[wrow][wc + c * 8] = wl[c];
        }
        __syncthreads();                 // W tile visible
        if (k0 + GBK < K) load_regs(k0 + GBK);   // overlaps MFMAs below

        #pragma unroll
        for (int ks = 0; ks < 2; ++ks)
            #pragma unroll
            for (int mj = 0; mj < 8; ++mj) {
                const int r = mj * 16 + row16;
                half8 b_hi = *(const half8*)&Whi[r][ks * 32 + quad * 8];
                half8 b_lo = *(const half8*)&Wlo[r][ks * 32 + quad * 8];
                #pragma unroll
                for (int ni = 0; ni < 2; ++ni) {
                    acc[ni][mj] = __builtin_amdgcn_mfma_f32_16x16x32_f16(
                        a_hi[ni][ks], b_hi, acc[ni][mj], 0, 0, 0);
                    acc[ni][mj] = __builtin_amdgcn_mfma_f32_16x16x32_f16(
                        a_hi[ni][ks], b_lo, acc[ni][mj], 0, 0, 0);
                    acc[ni][mj] = __builtin_amdgcn_mfma_f32_16x16x32_f16(
                        a_lo[ni][ks], b_hi, acc[ni][mj], 0, 0, 0);
                }
            }
    }

    #pragma unroll
    for (int ni = 0; ni < 2; ++ni)
        #pragma unroll
        for (int mj = 0; mj < 8; ++mj) {
            if (mode == 2) {
                const int s  = n0 + wave * 32 + ni * 16 + quad * 4;
                const int b  = s >> 11;
                const int sr = s & (S_ - 1);
                const int m  = m0 + mj * 16 + row16;
                const int h  = m >> 6;
                const int dk = m & 63;
                half4 h4;
                #pragma unroll
                for (int r = 0; r < 4; ++r) h4[r] = (_Float16)acc[ni][mj][r];
                *(half4*)((_Float16*)out0 +
                          (((size_t)b * H_ + h) * DK_ + dk) * S_ + sr) = h4;
            } else {
                #pragma unroll
                for (int rg = 0; rg < 4; ++rg) {
                    const int n = n0 + wave * 32 + ni * 16 + quad * 4 + rg;
                    const int m = m0 + mj * 16 + row16;
                    const float v = acc[ni][mj][rg];
                    if (mode == 0) {
                        ((float*)out0)[(size_t)n * D_ + m] = v;
                    } else {
                        const int b  = n >> 11;
                        const int s  = n & (S_ - 1);
                        const int h  = m >> 6;
                        const int dk = m & 63;
                        union { _Float16 h16; uint16_t u; } hi, lo;
                        hi.h16 = (_Float16)v;
                        lo.h16 = (_Float16)(v - (float)hi.h16);
                        uint32_t u = ((uint32_t)lo.u << 16) | (uint32_t)hi.u;
                        ((uint32_t*)out0)[(((size_t)b * H_ + h) * S_ + s) * DK_ + dk] = u;
                    }
                }
            }
        }
}

// ---------------------------------------------------------------------------
// MFMA flash attention v3 -- K-loop UNCHANGED from rounds 3-5 (proven: VGPR
// 80, no spill). Round-6 delta: epilogue writes packed u32 {lo16,hi16} into
// ONE buffer with 16-B/lane full-cache-line stores (round-3-5's two-plane
// 8-B stores caused WRITE_SIZE 70 MB vs 32 logical -> partial-line write
// amplification; round-0's full-line epilogue had WRITE == logical).
// ---------------------------------------------------------------------------
__global__ __launch_bounds__(256)
void attn_mfma(const uint32_t* __restrict__ Qhl, const uint32_t* __restrict__ Khl,
               const _Float16* __restrict__ Vth, uint32_t* __restrict__ Ahl) {
    __shared__ __align__(16) _Float16 KhiC[64][64];
    __shared__ __align__(16) _Float16 KloC[64][64];
    __shared__ __align__(16) _Float16 VC[64][64];
    __shared__ __align__(16) _Float16 PCT[4][16][72];   // [wave][q][k]

    const int bh = blockIdx.y;
    const int qt = (int)(gridDim.x - 1) - (int)blockIdx.x;  // heavy tiles first
    const int q0 = qt * 64;
    const int tid  = threadIdx.x;
    const int wave = tid >> 6;
    const int lane = tid & 63;
    const int c    = lane & 15;
    const int quad = lane >> 4;

    const uint32_t* Kb = Khl + (size_t)bh * S_ * DK_;
    const _Float16* Vb = Vth + (size_t)bh * DK_ * S_;

    // Q fragment (B-operand): lane holds q-row (q0+16w+c), k = ks*32+quad*8+j
    half8 qhi[2], qlo[2];
    {
        const uint32_t* Qrow = Qhl + ((size_t)bh * S_ + q0 + wave * 16 + c) * DK_;
        #pragma unroll
        for (int ks = 0; ks < 2; ++ks) {
            uint32_t u[8];
            *(uint4*)&u[0] = *(const uint4*)(Qrow + ks * 32 + quad * 8);
            *(uint4*)&u[4] = *(const uint4*)(Qrow + ks * 32 + quad * 8 + 4);
            union { half8 v; uint16_t s[8]; } hi, lo;
            #pragma unroll
            for (int j = 0; j < 8; ++j) {
                hi.s[j] = (uint16_t)(u[j] & 0xffffu);
                lo.s[j] = (uint16_t)(u[j] >> 16);
            }
            qhi[ks] = hi.v; qlo[ks] = lo.v;
        }
    }

    floatx4 acc_o[4];   // O^T: acc_o[dt][r] = O[q=lane-col][dk=dt*16+quad*4+r]
    const floatx4 zero4 = {0.f, 0.f, 0.f, 0.f};
    #pragma unroll
    for (int dt = 0; dt < 4; ++dt) acc_o[dt] = zero4;
    float mrun = -INFINITY, lrun = 0.f;

    // staging: thread -> (row srow, 16-elem segment); chunk = 8 halves = 16 B
    const int srow = tid >> 2;
    const int soff = (tid & 3) * 16;
    const int ch0  = (tid & 3) * 2;

    uint4 ku[4];
    uint4 vv[2];
    auto load_tile = [&](int kt) {
        const uint4* ksrc = (const uint4*)(Kb + (size_t)(kt * 64 + srow) * DK_ + soff);
        ku[0] = ksrc[0]; ku[1] = ksrc[1]; ku[2] = ksrc[2]; ku[3] = ksrc[3];
        const uint4* vsrc = (const uint4*)(Vb + (size_t)srow * S_ + kt * 64 + soff);
        vv[0] = vsrc[0]; vv[1] = vsrc[1];
    };
    auto write_tile = [&]() {
        #pragma unroll
        for (int hf = 0; hf < 2; ++hf) {
            const int swz = ((ch0 + hf) ^ (srow & 7)) * 8;
            uint32_t uu[8];
            *(uint4*)&uu[0] = ku[2 * hf];
            *(uint4*)&uu[4] = ku[2 * hf + 1];
            union { half8 v; uint16_t s[8]; } hi, lo;
            #pragma unroll
            for (int j = 0; j < 8; ++j) {
                hi.s[j] = (uint16_t)(uu[j] & 0xffffu);
                lo.s[j] = (uint16_t)(uu[j] >> 16);
            }
            *(half8*)&KhiC[srow][swz] = hi.v;
            *(half8*)&KloC[srow][swz] = lo.v;
            *(uint4*)&VC[srow][swz]   = vv[hf];
        }
    };

    const int qmy = q0 + wave * 16 + c;   // this lane's q-row
    const floatx4 neg4 = {-INFINITY, -INFINITY, -INFINITY, -INFINITY};

    load_tile(0);
    write_tile();

    for (int kt = 0; kt <= qt; ++kt) {
        const int k0 = kt * 64;
        const bool diag = (kt == qt);
        __syncthreads();                     // tile kt visible in LDS
        if (kt < qt) load_tile(kt + 1);      // prefetch overlaps compute

        // S^T tiles: sc[t][r] = S[q=qmy][k = k0 + t*16 + quad*4 + r] (unscaled)
        floatx4 sc[4];
        #pragma unroll
        for (int t = 0; t < 4; ++t) {
            if (diag && t > wave) { sc[t] = neg4; continue; }
            floatx4 s4 = zero4;
            const int krow = t * 16 + c;
            #pragma unroll
            for (int ks = 0; ks < 2; ++ks) {
                const int swz = ((ks * 4 + quad) ^ (krow & 7)) * 8;
                half8 kb = *(const half8*)&KhiC[krow][swz];
                half8 kl = *(const half8*)&KloC[krow][swz];
                s4 = __builtin_amdgcn_mfma_f32_16x16x32_f16(kb, qhi[ks], s4, 0, 0, 0);
                s4 = __builtin_amdgcn_mfma_f32_16x16x32_f16(kl, qhi[ks], s4, 0, 0, 0);
                s4 = __builtin_amdgcn_mfma_f32_16x16x32_f16(kb, qlo[ks], s4, 0, 0, 0);
            }
            #pragma unroll
            for (int r = 0; r < 4; ++r) s4[r] *= 0.125f;
            if (diag && t == wave) {
                #pragma unroll
                for (int r = 0; r < 4; ++r) {
                    const int k = k0 + t * 16 + quad * 4 + r;
                    if (k > qmy) s4[r] = -INFINITY;
                }
            }
            sc[t] = s4;
        }

        // online softmax: in-lane max over 16, 2 cross-quad shuffles
        float mx = -INFINITY;
        #pragma unroll
        for (int t = 0; t < 4; ++t)
            #pragma unroll
            for (int r = 0; r < 4; ++r) mx = fmaxf(mx, sc[t][r]);
        mx = fmaxf(mx, __shfl_xor(mx, 16));
        mx = fmaxf(mx, __shfl_xor(mx, 32));
        const float mnew  = fmaxf(mrun, mx);
        const float alpha = __expf(mrun - mnew);
        float ls = 0.f;
        #pragma unroll
        for (int t = 0; t < 4; ++t) {
            half4 p4;
            #pragma unroll
            for (int r = 0; r < 4; ++r) {
                const float p = __expf(sc[t][r] - mnew);
                ls += p;
                p4[r] = (_Float16)p;
            }
            // P^T store: PCT[wave][q=c][k-local = t*16+quad*4 .. +3]
            *(half4*)&PCT[wave][c][t * 16 + quad * 4] = p4;
        }
        lrun = alpha * lrun + ls;
        mrun = mnew;
        #pragma unroll
        for (int dt = 0; dt < 4; ++dt)
            #pragma unroll
            for (int r = 0; r < 4; ++r) acc_o[dt][r] *= alpha;

        // O^T += V^T P^T  (A-frag = V^T rows, B-frag = P rows; same-wave RAW)
        #pragma unroll
        for (int kc = 0; kc < 2; ++kc) {
            if (diag && kc == 1 && wave < 2) continue;   // P chunk all-zero
            half8 pb = *(const half8*)&PCT[wave][c][kc * 32 + quad * 8];
            #pragma unroll
            for (int dt = 0; dt < 4; ++dt) {
                const int vrow = dt * 16 + c;
                const int swz = ((kc * 4 + quad) ^ (vrow & 7)) * 8;
                half8 va = *(const half8*)&VC[vrow][swz];
                acc_o[dt] = __builtin_amdgcn_mfma_f32_16x16x32_f16(va, pb, acc_o[dt], 0, 0, 0);
            }
        }

        __syncthreads();                     // all reads of tile kt done
        if (kt < qt) write_tile();
    }

    // final l across quads, normalize, write packed u32 A [B,S,D] (full lines)
    float l = lrun;
    l += __shfl_xor(l, 16);
    l += __shfl_xor(l, 32);
    const float inv = 1.f / l;
    const int b = bh >> 4, h = bh & 15;
    uint32_t* dstA = Ahl + ((size_t)b * S_ + qmy) * D_ + h * DK_;
    #pragma unroll
    for (int dt = 0; dt < 4; ++dt) {
        uint4 pk;
        #pragma unroll
        for (int r = 0; r < 4; ++r) {
            const float o = acc_o[dt][r] * inv;
            union { _Float16 h16; uint16_t u; } hi, lo;
            hi.h16 = (_Float16)o;
            lo.h16 = (_Float16)(o - (float)hi.h16);
            ((uint32_t*)&pk)[r] = ((uint32_t)lo.u << 16) | (uint32_t)hi.u;
        }
        *(uint4*)(dstA + dt * 16 + quad * 4) = pk;
    }
}

// ---------------------------------------------------------------------------
extern "C" void kernel_launch(void* const* d_in, const int* in_sizes, int n_in,
                              void* d_out, int out_size, void* d_ws, size_t ws_size,
                              hipStream_t stream) {
    const float* q  = (const float*)d_in[0];
    const float* k  = (const float*)d_in[1];
    const float* v  = (const float*)d_in[2];
    const float* Wq = (const float*)d_in[3];
    const float* Wk = (const float*)d_in[4];
    const float* Wv = (const float*)d_in[5];
    const float* Wo = (const float*)d_in[6];
    float* out = (float*)d_out;

    const size_t SZ  = (size_t)B_ * S_ * D_;   // 8,388,608 elements
    const size_t WSZ = (size_t)D_ * D_;        // 1,048,576 elements

    // workspace layout (in halves): 7*SZ + 8*WSZ = 134.2 MB (proven footprint)
    _Float16* ws    = (_Float16*)d_ws;
    _Float16* xhi   = ws;                       // [NR, D]  (reused as A_u32)
    _Float16* xlo   = xhi + SZ;                 // [NR, D]
    _Float16* wbase = xlo + SZ;                 // 4 x {hi[D,D], lo[D,D]}
    uint32_t* Qhl = (uint32_t*)(wbase + 8 * WSZ);         // packed u32 (2*SZ halves)
    uint32_t* Khl = (uint32_t*)(wbase + 8 * WSZ + 2 * SZ);// packed u32 (2*SZ halves)
    _Float16* Vth = wbase + 8 * WSZ + 4 * SZ;   // f16 [B,H,DK,S] (SZ halves)
    uint32_t* Ahl = (uint32_t*)xhi;             // packed u32 [B,S,D] (2*SZ halves,
                                                //  x-planes dead after V GEMM)

    _Float16* wq_hi = wbase + 0 * 2 * WSZ, *wq_lo = wq_hi + WSZ;
    _Float16* wk_hi = wbase + 1 * 2 * WSZ, *wk_lo = wk_hi + WSZ;
    _Float16* wv_hi = wbase + 2 * 2 * WSZ, *wv_lo = wv_hi + WSZ;
    _Float16* wo_hi = wbase + 3 * 2 * WSZ, *wo_lo = wo_hi + WSZ;

    const int nx8 = (int)(SZ / 8);   // 1,048,576 -> 4096 blocks
    const int nw8 = (int)(WSZ / 8);  //   131,072 ->  512 blocks
    dim3 gb(NR_ / GBN, D_ / GBM);    // 64 x 8
    dim3 ga(S_ / 64, B_ * H_);       // 32 x 64
    dim3 gw(nw8 / 256, 4);           // 512 x 4

    split_w4<<<gw, 256, 0, stream>>>(Wq, Wk, Wv, Wo, wbase, nw8);

    split_f32<<<nx8 / 256, 256, 0, stream>>>(q, xhi, xlo, nx8);
    gemm_xwt_mfma<<<gb, 256, 0, stream>>>(xhi, xlo, wq_hi, wq_lo, Qhl, 1, 0);

    split_f32<<<nx8 / 256, 256, 0, stream>>>(k, xhi, xlo, nx8);
    gemm_xwt_mfma<<<gb, 256, 0, stream>>>(xhi, xlo, wk_hi, wk_lo, Khl, 1, 0);

    split_f32<<<nx8 / 256, 256, 0, stream>>>(v, xhi, xlo, nx8);
    gemm_xwt_mfma<<<gb, 256, 0, stream>>>(xhi, xlo, wv_hi, wv_lo, Vth, 2, 0);

    attn_mfma<<<ga, 256, 0, stream>>>(Qhl, Khl, Vth, Ahl);

    gemm_xwt_mfma<<<gb, 256, 0, stream>>>((const _Float16*)Ahl, nullptr,
                                          wo_hi, wo_lo, out, 0, 1);
}

// Round 7
// 578.657 us; speedup vs baseline: 1.5517x; 1.5517x over previous
//
#include <hip/hip_runtime.h>
#include <math.h>
#include <stdint.h>

#define B_  4
#define S_  2048
#define D_  1024
#define H_  16
#define DK_ 64
#define NR_ (B_ * S_)   // 8192 rows

typedef _Float16 half8  __attribute__((ext_vector_type(8)));
typedef _Float16 half4  __attribute__((ext_vector_type(4)));
typedef float    floatx4 __attribute__((ext_vector_type(4)));

// ---------------------------------------------------------------------------
// Batched weight split: all 4 weights in one launch (blockIdx.y selects).
// (X inputs are no longer pre-split: the GEMM splits fp32 A in-register.)
// ---------------------------------------------------------------------------
__global__ __launch_bounds__(256)
void split_w4(const float* __restrict__ w0, const float* __restrict__ w1,
              const float* __restrict__ w2, const float* __restrict__ w3,
              _Float16* __restrict__ wbase, int n8) {
    const int i = blockIdx.x * 256 + threadIdx.x;
    if (i >= n8) return;
    const float* src = (blockIdx.y == 0) ? w0 : (blockIdx.y == 1) ? w1 :
                       (blockIdx.y == 2) ? w2 : w3;
    _Float16* hi = wbase + (size_t)blockIdx.y * 2 * ((size_t)D_ * D_);
    _Float16* lo = hi + (size_t)D_ * D_;
    const float4* s4 = (const float4*)src;
    float4 a = s4[2 * i];
    float4 b = s4[2 * i + 1];
    float f[8] = {a.x, a.y, a.z, a.w, b.x, b.y, b.z, b.w};
    union { half8 v; _Float16 h[8]; } H, L;
    #pragma unroll
    for (int j = 0; j < 8; ++j) {
        _Float16 h = (_Float16)f[j];
        H.h[j] = h;
        L.h[j] = (_Float16)(f[j] - (float)h);
    }
    *(half8*)(hi + (size_t)i * 8) = H.v;
    *(half8*)(lo + (size_t)i * 8) = L.v;
}

// ---------------------------------------------------------------------------
// GEMM: out = X @ W^T via split-f16 MFMA (fp32-accurate), tile 128x128,
// GBK=32 (round-5 proven core: VGPR 72, no spill, ~83 us). A-fragments load
// directly global->register; only W (pre-split planes) staged in LDS.
// Round-7: APACK is a TEMPLATE param (round-6 lesson: a runtime flag makes
// one regalloc cover the worst path -> spill for every caller).
//   APACK=0: X is raw fp32 [NR,D]; hi/lo split happens in-register during
//            the A prefetch (same 32 B/lane/frag as two f16 planes; ~64
//            VALU/iter hidden under 48 MFMAs on the separate VALU pipe).
//            This deletes the 3 split_f32 pre-passes entirely.
//   APACK=1: X is packed u32 {lo16,hi16} [NR,D] (attention output).
// Epilogue modes:
//   0: fp32 [N x M] row-major                        (Wo projection -> d_out)
//   1: packed u32 {lo16,hi16} f16 split, [B,H,S,DK]  (Q,K projections)
//   2: f16 transposed head-split [B,H,DK,S]          (V projection)
// ---------------------------------------------------------------------------
#define GBN 128
#define GBM 128
#define GBK 32
#define LDH 40

template <int APACK>
__global__ __launch_bounds__(256, 3)
void gemm_xwt_mfma(const void* __restrict__ Xin,
                   const _Float16* __restrict__ Wh, const _Float16* __restrict__ Wl,
                   void* __restrict__ out0, int mode) {
    __shared__ __align__(16) _Float16 Whi[GBM][LDH];
    __shared__ __align__(16) _Float16 Wlo[GBM][LDH];
    const int K = D_;

    const int tid  = threadIdx.x;
    const int wave = tid >> 6;
    const int lane = tid & 63;
    const int row16 = lane & 15;
    const int quad  = lane >> 4;
    const int n0 = blockIdx.x * GBN;
    const int m0 = blockIdx.y * GBM;

    // W staging map: 128 rows x 32 halves/plane, 2 threads/row (16 each)
    const int wrow = tid >> 1;
    const int wc   = (tid & 1) << 4;

    // A bases: lane (row16,quad) covers X[n0+wave*32+ni*16+row16][k0+quad*8..+8]
    const float*    aFb = (const float*)Xin +
                          (size_t)(n0 + wave * 32 + row16) * K + quad * 8;
    const uint32_t* aPb = (const uint32_t*)Xin +
                          (size_t)(n0 + wave * 32 + row16) * K + quad * 8;

    floatx4 acc[2][8];
    const floatx4 zero4 = {0.f, 0.f, 0.f, 0.f};
    #pragma unroll
    for (int i = 0; i < 2; ++i)
        #pragma unroll
        for (int j = 0; j < 8; ++j) acc[i][j] = zero4;

    half8 pa_h[2], pa_l[2];
    uint4 wh0, wh1, wl0, wl1;
    auto load_regs = [&](int k0) {
        #pragma unroll
        for (int ni = 0; ni < 2; ++ni) {
            if (APACK == 0) {
                // raw fp32 A: load 8 floats, split hi/lo in-register
                const float* p = aFb + (size_t)ni * 16 * K + k0;
                float4 f0 = *(const float4*)p;
                float4 f1 = *(const float4*)(p + 4);
                float f[8] = {f0.x, f0.y, f0.z, f0.w, f1.x, f1.y, f1.z, f1.w};
                union { half8 v; _Float16 h[8]; } hi, lo;
                #pragma unroll
                for (int j = 0; j < 8; ++j) {
                    _Float16 h = (_Float16)f[j];
                    hi.h[j] = h;
                    lo.h[j] = (_Float16)(f[j] - (float)h);
                }
                pa_h[ni] = hi.v;
                pa_l[ni] = lo.v;
            } else {
                // packed u32 {lo16,hi16} A: unpack
                const uint32_t* p = aPb + (size_t)ni * 16 * K + k0;
                uint32_t u[8];
                *(uint4*)&u[0] = *(const uint4*)p;
                *(uint4*)&u[4] = *(const uint4*)(p + 4);
                union { half8 v; uint16_t s[8]; } hi, lo;
                #pragma unroll
                for (int j = 0; j < 8; ++j) {
                    hi.s[j] = (uint16_t)(u[j] & 0xffffu);
                    lo.s[j] = (uint16_t)(u[j] >> 16);
                }
                pa_h[ni] = hi.v;
                pa_l[ni] = lo.v;
            }
        }
        const _Float16* pwh = Wh + (size_t)(m0 + wrow) * K + k0 + wc;
        const _Float16* pwl = Wl + (size_t)(m0 + wrow) * K + k0 + wc;
        wh0 = *(const uint4*)pwh;
        wh1 = *(const uint4*)(pwh + 8);
        wl0 = *(const uint4*)pwl;
        wl1 = *(const uint4*)(pwl + 8);
    };

    load_regs(0);
    for (int k0 = 0; k0 < K; k0 += GBK) {
        // capture current A-frags before prefetch overwrites them
        half8 a_hi[2] = {pa_h[0], pa_h[1]};
        half8 a_lo[2] = {pa_l[0], pa_l[1]};
        __syncthreads();                 // prev iteration's b-reads done
        *(uint4*)&Whi[wrow][wc]     = wh0;
        *(uint4*)&Whi[wrow][wc + 8] = wh1;
        *(uint4*)&Wlo[wrow][wc]     = wl0;
        *(uint4*)&Wlo[wrow][wc + 8] = wl1;
        __syncthreads();                 // W tile visible
        if (k0 + GBK < K) load_regs(k0 + GBK);   // overlaps MFMAs below

        #pragma unroll
        for (int mj = 0; mj < 8; ++mj) {
            const int r = mj * 16 + row16;
            half8 b_hi = *(const half8*)&Whi[r][quad * 8];
            half8 b_lo = *(const half8*)&Wlo[r][quad * 8];
            #pragma unroll
            for (int ni = 0; ni < 2; ++ni) {
                acc[ni][mj] = __builtin_amdgcn_mfma_f32_16x16x32_f16(
                    a_hi[ni], b_hi, acc[ni][mj], 0, 0, 0);
                acc[ni][mj] = __builtin_amdgcn_mfma_f32_16x16x32_f16(
                    a_hi[ni], b_lo, acc[ni][mj], 0, 0, 0);
                acc[ni][mj] = __builtin_amdgcn_mfma_f32_16x16x32_f16(
                    a_lo[ni], b_hi, acc[ni][mj], 0, 0, 0);
            }
        }
    }

    #pragma unroll
    for (int ni = 0; ni < 2; ++ni)
        #pragma unroll
        for (int mj = 0; mj < 8; ++mj) {
            if (mode == 2) {
                const int s  = n0 + wave * 32 + ni * 16 + quad * 4;
                const int b  = s >> 11;
                const int sr = s & (S_ - 1);
                const int m  = m0 + mj * 16 + row16;
                const int h  = m >> 6;
                const int dk = m & 63;
                half4 h4;
                #pragma unroll
                for (int r = 0; r < 4; ++r) h4[r] = (_Float16)acc[ni][mj][r];
                *(half4*)((_Float16*)out0 +
                          (((size_t)b * H_ + h) * DK_ + dk) * S_ + sr) = h4;
            } else {
                #pragma unroll
                for (int rg = 0; rg < 4; ++rg) {
                    const int n = n0 + wave * 32 + ni * 16 + quad * 4 + rg;
                    const int m = m0 + mj * 16 + row16;
                    const float v = acc[ni][mj][rg];
                    if (mode == 0) {
                        ((float*)out0)[(size_t)n * D_ + m] = v;
                    } else {
                        const int b  = n >> 11;
                        const int s  = n & (S_ - 1);
                        const int h  = m >> 6;
                        const int dk = m & 63;
                        union { _Float16 h16; uint16_t u; } hi, lo;
                        hi.h16 = (_Float16)v;
                        lo.h16 = (_Float16)(v - (float)hi.h16);
                        uint32_t u = ((uint32_t)lo.u << 16) | (uint32_t)hi.u;
                        ((uint32_t*)out0)[(((size_t)b * H_ + h) * S_ + s) * DK_ + dk] = u;
                    }
                }
            }
        }
}

// ---------------------------------------------------------------------------
// MFMA flash attention v3 -- UNCHANGED from round 6 (proven: VGPR 80, no
// spill, ~237 us). Q/K packed u32 {lo16,hi16}; V f16 [B,H,DK,S]; output
// packed u32 {lo16,hi16} A [B,S,D] (consumed by the APACK=1 Wo GEMM).
// ---------------------------------------------------------------------------
__global__ __launch_bounds__(256)
void attn_mfma(const uint32_t* __restrict__ Qhl, const uint32_t* __restrict__ Khl,
               const _Float16* __restrict__ Vth, uint32_t* __restrict__ Ahl) {
    __shared__ __align__(16) _Float16 KhiC[64][64];
    __shared__ __align__(16) _Float16 KloC[64][64];
    __shared__ __align__(16) _Float16 VC[64][64];
    __shared__ __align__(16) _Float16 PCT[4][16][72];   // [wave][q][k]

    const int bh = blockIdx.y;
    const int qt = (int)(gridDim.x - 1) - (int)blockIdx.x;  // heavy tiles first
    const int q0 = qt * 64;
    const int tid  = threadIdx.x;
    const int wave = tid >> 6;
    const int lane = tid & 63;
    const int c    = lane & 15;
    const int quad = lane >> 4;

    const uint32_t* Kb = Khl + (size_t)bh * S_ * DK_;
    const _Float16* Vb = Vth + (size_t)bh * DK_ * S_;

    // Q fragment (B-operand): lane holds q-row (q0+16w+c), k = ks*32+quad*8+j
    half8 qhi[2], qlo[2];
    {
        const uint32_t* Qrow = Qhl + ((size_t)bh * S_ + q0 + wave * 16 + c) * DK_;
        #pragma unroll
        for (int ks = 0; ks < 2; ++ks) {
            uint32_t u[8];
            *(uint4*)&u[0] = *(const uint4*)(Qrow + ks * 32 + quad * 8);
            *(uint4*)&u[4] = *(const uint4*)(Qrow + ks * 32 + quad * 8 + 4);
            union { half8 v; uint16_t s[8]; } hi, lo;
            #pragma unroll
            for (int j = 0; j < 8; ++j) {
                hi.s[j] = (uint16_t)(u[j] & 0xffffu);
                lo.s[j] = (uint16_t)(u[j] >> 16);
            }
            qhi[ks] = hi.v; qlo[ks] = lo.v;
        }
    }

    floatx4 acc_o[4];   // O^T: acc_o[dt][r] = O[q=lane-col][dk=dt*16+quad*4+r]
    const floatx4 zero4 = {0.f, 0.f, 0.f, 0.f};
    #pragma unroll
    for (int dt = 0; dt < 4; ++dt) acc_o[dt] = zero4;
    float mrun = -INFINITY, lrun = 0.f;

    // staging: thread -> (row srow, 16-elem segment); chunk = 8 halves = 16 B
    const int srow = tid >> 2;
    const int soff = (tid & 3) * 16;
    const int ch0  = (tid & 3) * 2;

    uint4 ku[4];
    uint4 vv[2];
    auto load_tile = [&](int kt) {
        const uint4* ksrc = (const uint4*)(Kb + (size_t)(kt * 64 + srow) * DK_ + soff);
        ku[0] = ksrc[0]; ku[1] = ksrc[1]; ku[2] = ksrc[2]; ku[3] = ksrc[3];
        const uint4* vsrc = (const uint4*)(Vb + (size_t)srow * S_ + kt * 64 + soff);
        vv[0] = vsrc[0]; vv[1] = vsrc[1];
    };
    auto write_tile = [&]() {
        #pragma unroll
        for (int hf = 0; hf < 2; ++hf) {
            const int swz = ((ch0 + hf) ^ (srow & 7)) * 8;
            uint32_t uu[8];
            *(uint4*)&uu[0] = ku[2 * hf];
            *(uint4*)&uu[4] = ku[2 * hf + 1];
            union { half8 v; uint16_t s[8]; } hi, lo;
            #pragma unroll
            for (int j = 0; j < 8; ++j) {
                hi.s[j] = (uint16_t)(uu[j] & 0xffffu);
                lo.s[j] = (uint16_t)(uu[j] >> 16);
            }
            *(half8*)&KhiC[srow][swz] = hi.v;
            *(half8*)&KloC[srow][swz] = lo.v;
            *(uint4*)&VC[srow][swz]   = vv[hf];
        }
    };

    const int qmy = q0 + wave * 16 + c;   // this lane's q-row
    const floatx4 neg4 = {-INFINITY, -INFINITY, -INFINITY, -INFINITY};

    load_tile(0);
    write_tile();

    for (int kt = 0; kt <= qt; ++kt) {
        const int k0 = kt * 64;
        const bool diag = (kt == qt);
        __syncthreads();                     // tile kt visible in LDS
        if (kt < qt) load_tile(kt + 1);      // prefetch overlaps compute

        // S^T tiles: sc[t][r] = S[q=qmy][k = k0 + t*16 + quad*4 + r] (unscaled)
        floatx4 sc[4];
        #pragma unroll
        for (int t = 0; t < 4; ++t) {
            if (diag && t > wave) { sc[t] = neg4; continue; }
            floatx4 s4 = zero4;
            const int krow = t * 16 + c;
            #pragma unroll
            for (int ks = 0; ks < 2; ++ks) {
                const int swz = ((ks * 4 + quad) ^ (krow & 7)) * 8;
                half8 kb = *(const half8*)&KhiC[krow][swz];
                half8 kl = *(const half8*)&KloC[krow][swz];
                s4 = __builtin_amdgcn_mfma_f32_16x16x32_f16(kb, qhi[ks], s4, 0, 0, 0);
                s4 = __builtin_amdgcn_mfma_f32_16x16x32_f16(kl, qhi[ks], s4, 0, 0, 0);
                s4 = __builtin_amdgcn_mfma_f32_16x16x32_f16(kb, qlo[ks], s4, 0, 0, 0);
            }
            #pragma unroll
            for (int r = 0; r < 4; ++r) s4[r] *= 0.125f;
            if (diag && t == wave) {
                #pragma unroll
                for (int r = 0; r < 4; ++r) {
                    const int k = k0 + t * 16 + quad * 4 + r;
                    if (k > qmy) s4[r] = -INFINITY;
                }
            }
            sc[t] = s4;
        }

        // online softmax: in-lane max over 16, 2 cross-quad shuffles
        float mx = -INFINITY;
        #pragma unroll
        for (int t = 0; t < 4; ++t)
            #pragma unroll
            for (int r = 0; r < 4; ++r) mx = fmaxf(mx, sc[t][r]);
        mx = fmaxf(mx, __shfl_xor(mx, 16));
        mx = fmaxf(mx, __shfl_xor(mx, 32));
        const float mnew  = fmaxf(mrun, mx);
        const float alpha = __expf(mrun - mnew);
        float ls = 0.f;
        #pragma unroll
        for (int t = 0; t < 4; ++t) {
            half4 p4;
            #pragma unroll
            for (int r = 0; r < 4; ++r) {
                const float p = __expf(sc[t][r] - mnew);
                ls += p;
                p4[r] = (_Float16)p;
            }
            // P^T store: PCT[wave][q=c][k-local = t*16+quad*4 .. +3]
            *(half4*)&PCT[wave][c][t * 16 + quad * 4] = p4;
        }
        lrun = alpha * lrun + ls;
        mrun = mnew;
        #pragma unroll
        for (int dt = 0; dt < 4; ++dt)
            #pragma unroll
            for (int r = 0; r < 4; ++r) acc_o[dt][r] *= alpha;

        // O^T += V^T P^T  (A-frag = V^T rows, B-frag = P rows; same-wave RAW)
        #pragma unroll
        for (int kc = 0; kc < 2; ++kc) {
            if (diag && kc == 1 && wave < 2) continue;   // P chunk all-zero
            half8 pb = *(const half8*)&PCT[wave][c][kc * 32 + quad * 8];
            #pragma unroll
            for (int dt = 0; dt < 4; ++dt) {
                const int vrow = dt * 16 + c;
                const int swz = ((kc * 4 + quad) ^ (vrow & 7)) * 8;
                half8 va = *(const half8*)&VC[vrow][swz];
                acc_o[dt] = __builtin_amdgcn_mfma_f32_16x16x32_f16(va, pb, acc_o[dt], 0, 0, 0);
            }
        }

        __syncthreads();                     // all reads of tile kt done
        if (kt < qt) write_tile();
    }

    // final l across quads, normalize, write packed u32 A [B,S,D]
    float l = lrun;
    l += __shfl_xor(l, 16);
    l += __shfl_xor(l, 32);
    const float inv = 1.f / l;
    const int b = bh >> 4, h = bh & 15;
    uint32_t* dstA = Ahl + ((size_t)b * S_ + qmy) * D_ + h * DK_;
    #pragma unroll
    for (int dt = 0; dt < 4; ++dt) {
        uint4 pk;
        #pragma unroll
        for (int r = 0; r < 4; ++r) {
            const float o = acc_o[dt][r] * inv;
            union { _Float16 h16; uint16_t u; } hi, lo;
            hi.h16 = (_Float16)o;
            lo.h16 = (_Float16)(o - (float)hi.h16);
            ((uint32_t*)&pk)[r] = ((uint32_t)lo.u << 16) | (uint32_t)hi.u;
        }
        *(uint4*)(dstA + dt * 16 + quad * 4) = pk;
    }
}

// ---------------------------------------------------------------------------
extern "C" void kernel_launch(void* const* d_in, const int* in_sizes, int n_in,
                              void* d_out, int out_size, void* d_ws, size_t ws_size,
                              hipStream_t stream) {
    const float* q  = (const float*)d_in[0];
    const float* k  = (const float*)d_in[1];
    const float* v  = (const float*)d_in[2];
    const float* Wq = (const float*)d_in[3];
    const float* Wk = (const float*)d_in[4];
    const float* Wv = (const float*)d_in[5];
    const float* Wo = (const float*)d_in[6];
    float* out = (float*)d_out;

    const size_t SZ  = (size_t)B_ * S_ * D_;   // 8,388,608 elements
    const size_t WSZ = (size_t)D_ * D_;        // 1,048,576 elements

    // workspace layout (in halves): 8*WSZ + 7*SZ = 134.2 MB (proven footprint)
    _Float16* ws    = (_Float16*)d_ws;
    _Float16* wbase = ws;                               // 4 x {hi[D,D], lo[D,D]}
    uint32_t* Qhl = (uint32_t*)(wbase + 8 * WSZ);       // packed u32 (2*SZ halves)
    uint32_t* Khl = (uint32_t*)(wbase + 8 * WSZ + 2 * SZ);  // packed u32 (2*SZ)
    _Float16* Vth = wbase + 8 * WSZ + 4 * SZ;           // f16 [B,H,DK,S] (SZ)
    uint32_t* Ahl = (uint32_t*)(wbase + 8 * WSZ + 5 * SZ);  // packed u32 (2*SZ)

    _Float16* wq_hi = wbase + 0 * 2 * WSZ, *wq_lo = wq_hi + WSZ;
    _Float16* wk_hi = wbase + 1 * 2 * WSZ, *wk_lo = wk_hi + WSZ;
    _Float16* wv_hi = wbase + 2 * 2 * WSZ, *wv_lo = wv_hi + WSZ;
    _Float16* wo_hi = wbase + 3 * 2 * WSZ, *wo_lo = wo_hi + WSZ;

    const int nw8 = (int)(WSZ / 8);  // 131,072 -> 512 blocks
    dim3 gb(NR_ / GBN, D_ / GBM);    // 64 x 8
    dim3 ga(S_ / 64, B_ * H_);       // 32 x 64
    dim3 gw(nw8 / 256, 4);           // 512 x 4

    split_w4<<<gw, 256, 0, stream>>>(Wq, Wk, Wv, Wo, wbase, nw8);

    gemm_xwt_mfma<0><<<gb, 256, 0, stream>>>(q, wq_hi, wq_lo, Qhl, 1);
    gemm_xwt_mfma<0><<<gb, 256, 0, stream>>>(k, wk_hi, wk_lo, Khl, 1);
    gemm_xwt_mfma<0><<<gb, 256, 0, stream>>>(v, wv_hi, wv_lo, Vth, 2);

    attn_mfma<<<ga, 256, 0, stream>>>(Qhl, Khl, Vth, Ahl);

    gemm_xwt_mfma<1><<<gb, 256, 0, stream>>>(Ahl, wo_hi, wo_lo, out, 0);
}